// Round 1
// baseline (62.776 us; speedup 1.0000x reference)
//
#include <hip/hip_runtime.h>

#define NTOK 16384
#define TB 32

typedef float f32x4_t __attribute__((ext_vector_type(4)));
typedef short s16x8_t __attribute__((ext_vector_type(8)));

__device__ __forceinline__ unsigned short f2bf(float f) {
    unsigned int x = __float_as_uint(f);
    x += 0x7fffu + ((x >> 16) & 1u);
    return (unsigned short)(x >> 16);
}
__device__ __forceinline__ float fexp2(float x) {
#if __has_builtin(__builtin_amdgcn_exp2f)
    return __builtin_amdgcn_exp2f(x);
#else
    return exp2f(x);
#endif
}
__device__ __forceinline__ float frcp(float x) {
#if __has_builtin(__builtin_amdgcn_rcpf)
    return __builtin_amdgcn_rcpf(x);
#else
    return 1.0f / x;
#endif
}
__device__ __forceinline__ float frsq(float x) {
#if __has_builtin(__builtin_amdgcn_rsqf)
    return __builtin_amdgcn_rsqf(x);
#else
    return rsqrtf(x);
#endif
}

__global__ __launch_bounds__(256, 2)
void tf3_kernel(const float* __restrict__ x,
                const float* __restrict__ W1, const float* __restrict__ b1,
                const float* __restrict__ Wq, const float* __restrict__ bq,
                const float* __restrict__ Wk, const float* __restrict__ bk,
                const float* __restrict__ Wv, const float* __restrict__ bv,
                const float* __restrict__ Wf1, const float* __restrict__ bf1,
                const float* __restrict__ Wf2, const float* __restrict__ bf2,
                const float* __restrict__ lng, const float* __restrict__ lnb,
                const float* __restrict__ Wout, const float* __restrict__ bout,
                float* __restrict__ out)
{
    // LDS: weight chunk (bf16, transposed+swizzled), activation chunk (bf16, swizzled),
    // Q (f32), K->Y->A (f32, stride 68 pad), V (f32), biases/LN params.  ~37.5 KB total.
    __shared__ __align__(16) unsigned short w_lds[64 * 64];
    __shared__ __align__(16) unsigned short a_lds[TB * 64];
    __shared__ __align__(16) float q_lds[TB * 64];
    __shared__ __align__(16) float ky_lds[TB * 68];
    __shared__ __align__(16) float v_lds[TB * 64];
    __shared__ float bias_lds[64];
    __shared__ float lng_lds[64];
    __shared__ float lnb_lds[64];

    const int tid = threadIdx.x;
    const int wv  = tid >> 6;    // wave 0..3
    const int l   = tid & 63;    // lane
    const int n0  = blockIdx.x * TB;

    // MFMA geometry: wave (wv&1) owns 16-row slab, (wv>>1) owns 32-col pair
    const int srow = (wv & 1) * 16;
    const int pcol = (wv >> 1) * 32;
    const int lr   = l & 15;
    const int q4   = l >> 4;

    float res_reg[8], cur_reg[8];

    // cooperative: global fp32 [64][64] (k-major) -> w_lds transposed [m][k] bf16, XOR-swizzled chunks
    auto load_w = [&](const float* __restrict__ Wg) {
        #pragma unroll
        for (int h8 = 0; h8 < 2; ++h8) {
            const int cc = wv * 2 + h8;            // k-chunk 0..7
            s16x8_t pk;
            #pragma unroll
            for (int e = 0; e < 8; ++e)
                pk[e] = (short)f2bf(Wg[(cc * 8 + e) * 64 + l]);   // coalesced per e
            *reinterpret_cast<s16x8_t*>(&w_lds[l * 64 + ((cc ^ (l & 7)) * 8)]) = pk;
        }
    };

    // ---------------- stage 0: h = x @ W1 + b1 (K=256 in 4 chunks) ----------------
    f32x4_t acc0 = {0.f, 0.f, 0.f, 0.f};
    f32x4_t acc1 = {0.f, 0.f, 0.f, 0.f};
    for (int kc = 0; kc < 4; ++kc) {
        __syncthreads();
        {   // stage x chunk: 32 rows x 64 cols -> a_lds bf16 swizzled
            const int r  = tid >> 3;
            const int cc = tid & 7;
            const float* xp = x + (size_t)(n0 + r) * 256 + kc * 64 + cc * 8;
            const float4 u0 = *reinterpret_cast<const float4*>(xp);
            const float4 u1 = *reinterpret_cast<const float4*>(xp + 4);
            s16x8_t pk;
            pk[0] = (short)f2bf(u0.x); pk[1] = (short)f2bf(u0.y);
            pk[2] = (short)f2bf(u0.z); pk[3] = (short)f2bf(u0.w);
            pk[4] = (short)f2bf(u1.x); pk[5] = (short)f2bf(u1.y);
            pk[6] = (short)f2bf(u1.z); pk[7] = (short)f2bf(u1.w);
            *reinterpret_cast<s16x8_t*>(&a_lds[r * 64 + ((cc ^ (r & 7)) * 8)]) = pk;
        }
        {   // stage W1 chunk transposed
            #pragma unroll
            for (int h8 = 0; h8 < 2; ++h8) {
                const int cc = wv * 2 + h8;
                s16x8_t pk;
                #pragma unroll
                for (int e = 0; e < 8; ++e)
                    pk[e] = (short)f2bf(W1[(size_t)(kc * 64 + cc * 8 + e) * 64 + l]);
                *reinterpret_cast<s16x8_t*>(&w_lds[l * 64 + ((cc ^ (l & 7)) * 8)]) = pk;
            }
        }
        __syncthreads();
        #pragma unroll
        for (int kh = 0; kh < 2; ++kh) {
            const int ck = kh * 4 + q4;
            const int ar = srow + lr;
            const s16x8_t af = *reinterpret_cast<const s16x8_t*>(&a_lds[ar * 64 + ((ck ^ (ar & 7)) * 8)]);
            const int c0 = pcol + lr;
            const int c1 = pcol + 16 + lr;
            const s16x8_t b0  = *reinterpret_cast<const s16x8_t*>(&w_lds[c0 * 64 + ((ck ^ (c0 & 7)) * 8)]);
            const s16x8_t b1v = *reinterpret_cast<const s16x8_t*>(&w_lds[c1 * 64 + ((ck ^ (c1 & 7)) * 8)]);
            acc0 = __builtin_amdgcn_mfma_f32_16x16x32_bf16(af, b0,  acc0, 0, 0, 0);
            acc1 = __builtin_amdgcn_mfma_f32_16x16x32_bf16(af, b1v, acc1, 0, 0, 0);
        }
    }
    __syncthreads();
    if (tid < 64) bias_lds[tid] = b1[tid];
    __syncthreads();
    #pragma unroll
    for (int rg = 0; rg < 4; ++rg) {   // h fragments -> q_lds (row-major redistribute)
        const int tr = srow + q4 * 4 + rg;
        q_lds[tr * 64 + pcol + lr]      = acc0[rg] + bias_lds[pcol + lr];
        q_lds[tr * 64 + pcol + 16 + lr] = acc1[rg] + bias_lds[pcol + 16 + lr];
    }
    __syncthreads();
    #pragma unroll
    for (int tt = 0; tt < 8; ++tt) {   // cur = h, res = leaky(h, 0.1)
        const int t = wv * 8 + tt;
        const float h = q_lds[t * 64 + l];
        cur_reg[tt] = h;
        res_reg[tt] = h >= 0.f ? h : 0.1f * h;
        a_lds[t * 64 + ((((l >> 3) ^ (t & 7)) * 8) + (l & 7))] = f2bf(h);
    }

    // ---------------- 3 attention stages ----------------
    for (int st = 0; st < 3; ++st) {
        const float* Wmat[5] = { Wq + st * 4096, Wk + st * 4096, Wv + st * 4096,
                                 Wf1 + st * 4096, Wf2 + st * 4096 };
        const float* bvec[5] = { bq + st * 64, bk + st * 64, bv + st * 64,
                                 bf1 + st * 64, bf2 + st * 64 };

        // ---- Q, K, V projections ----
        #pragma unroll
        for (int mm = 0; mm < 3; ++mm) {
            __syncthreads();
            load_w(Wmat[mm]);
            if (tid < 64) bias_lds[tid] = bvec[mm][tid];
            if (mm == 0) {
                if (tid >= 64 && tid < 128)  lng_lds[tid - 64]  = lng[st * 64 + tid - 64];
                if (tid >= 128 && tid < 192) lnb_lds[tid - 128] = lnb[st * 64 + tid - 128];
            }
            __syncthreads();
            f32x4_t a0 = {0.f,0.f,0.f,0.f}, a1 = {0.f,0.f,0.f,0.f};
            #pragma unroll
            for (int kh = 0; kh < 2; ++kh) {
                const int ck = kh * 4 + q4;
                const int ar = srow + lr;
                const s16x8_t af = *reinterpret_cast<const s16x8_t*>(&a_lds[ar * 64 + ((ck ^ (ar & 7)) * 8)]);
                const int c0 = pcol + lr;
                const int c1 = pcol + 16 + lr;
                const s16x8_t b0  = *reinterpret_cast<const s16x8_t*>(&w_lds[c0 * 64 + ((ck ^ (c0 & 7)) * 8)]);
                const s16x8_t b1v = *reinterpret_cast<const s16x8_t*>(&w_lds[c1 * 64 + ((ck ^ (c1 & 7)) * 8)]);
                a0 = __builtin_amdgcn_mfma_f32_16x16x32_bf16(af, b0,  a0, 0, 0, 0);
                a1 = __builtin_amdgcn_mfma_f32_16x16x32_bf16(af, b1v, a1, 0, 0, 0);
            }
            #pragma unroll
            for (int rg = 0; rg < 4; ++rg) {
                const int tr = srow + q4 * 4 + rg;
                const int c0 = pcol + lr;
                const int c1 = pcol + 16 + lr;
                const float o0 = a0[rg] + bias_lds[c0];
                const float o1 = a1[rg] + bias_lds[c1];
                if (mm == 0)      { q_lds[tr * 64 + c0] = o0; q_lds[tr * 64 + c1] = o1; }
                else if (mm == 1) { ky_lds[tr * 68 + c0] = o0; ky_lds[tr * 68 + c1] = o1; }
                else              { v_lds[tr * 64 + c0] = o0; v_lds[tr * 64 + c1] = o1; }
            }
        }
        __syncthreads();

        // ---- attention core: y_i = sum_j softmax_j(q_i k_j) v_j + cur_i ----
        #pragma unroll
        for (int tt = 0; tt < 8; ++tt) {
            const int t = wv * 8 + tt;
            const float qv   = q_lds[t * 64 + l];
            const float kown = ky_lds[t * 68 + l];
            float kmax = kown, kmin = kown;
            #pragma unroll
            for (int m = 1; m < 64; m <<= 1) {
                kmax = fmaxf(kmax, __shfl_xor(kmax, m, 64));
                kmin = fminf(kmin, __shfl_xor(kmin, m, 64));
            }
            const float qs = qv * 1.44269504088896340736f;       // q * log2(e)
            const float m2 = fmaxf(qs * kmax, qs * kmin);        // exact row max (rank-1 scores)
            float s0 = 0.f, s1 = 0.f, p0 = 0.f, p1 = 0.f;
            #pragma unroll
            for (int j = 0; j < 64; j += 4) {
                const float4 kj = *reinterpret_cast<const float4*>(&ky_lds[t * 68 + j]); // uniform bcast
                const float4 vj = *reinterpret_cast<const float4*>(&v_lds[t * 64 + j]);
                const float e0 = fexp2(fmaf(qs, kj.x, -m2));
                const float e1 = fexp2(fmaf(qs, kj.y, -m2));
                const float e2 = fexp2(fmaf(qs, kj.z, -m2));
                const float e3 = fexp2(fmaf(qs, kj.w, -m2));
                s0 += e0 + e2; s1 += e1 + e3;
                p0 = fmaf(e0, vj.x, p0); p1 = fmaf(e1, vj.y, p1);
                p0 = fmaf(e2, vj.z, p0); p1 = fmaf(e3, vj.w, p1);
            }
            const float y = (p0 + p1) * frcp(s0 + s1) + cur_reg[tt];
            ky_lds[t * 68 + l] = y;   // Y overwrites K row (fully consumed; same wave only)
        }
        __syncthreads();

        // ---- F1: h1 = leaky(Y @ Wf1 + bf1, 0.01) ----
        load_w(Wmat[3]);
        if (tid < 64) bias_lds[tid] = bvec[3][tid];
        __syncthreads();
        {
            f32x4_t a0 = {0.f,0.f,0.f,0.f}, a1 = {0.f,0.f,0.f,0.f};
            #pragma unroll
            for (int kh = 0; kh < 2; ++kh) {
                const int ar = srow + lr;
                const float* yp = &ky_lds[ar * 68 + kh * 32 + q4 * 8];
                const float4 y0 = *reinterpret_cast<const float4*>(yp);
                const float4 y1 = *reinterpret_cast<const float4*>(yp + 4);
                s16x8_t af;
                af[0] = (short)f2bf(y0.x); af[1] = (short)f2bf(y0.y);
                af[2] = (short)f2bf(y0.z); af[3] = (short)f2bf(y0.w);
                af[4] = (short)f2bf(y1.x); af[5] = (short)f2bf(y1.y);
                af[6] = (short)f2bf(y1.z); af[7] = (short)f2bf(y1.w);
                const int ck = kh * 4 + q4;
                const int c0 = pcol + lr;
                const int c1 = pcol + 16 + lr;
                const s16x8_t b0  = *reinterpret_cast<const s16x8_t*>(&w_lds[c0 * 64 + ((ck ^ (c0 & 7)) * 8)]);
                const s16x8_t b1v = *reinterpret_cast<const s16x8_t*>(&w_lds[c1 * 64 + ((ck ^ (c1 & 7)) * 8)]);
                a0 = __builtin_amdgcn_mfma_f32_16x16x32_bf16(af, b0,  a0, 0, 0, 0);
                a1 = __builtin_amdgcn_mfma_f32_16x16x32_bf16(af, b1v, a1, 0, 0, 0);
            }
            #pragma unroll
            for (int rg = 0; rg < 4; ++rg) {
                const int tr = srow + q4 * 4 + rg;
                const int c0 = pcol + lr;
                const int c1 = pcol + 16 + lr;
                float h0 = a0[rg] + bias_lds[c0]; h0 = h0 >= 0.f ? h0 : 0.01f * h0;
                float h1 = a1[rg] + bias_lds[c1]; h1 = h1 >= 0.f ? h1 : 0.01f * h1;
                a_lds[tr * 64 + (((c0 >> 3) ^ (tr & 7)) * 8) + (c0 & 7)] = f2bf(h0);
                a_lds[tr * 64 + (((c1 >> 3) ^ (tr & 7)) * 8) + (c1 & 7)] = f2bf(h1);
            }
        }
        __syncthreads();

        // ---- F2: A = h1 @ Wf2 + bf2 + Y ----
        load_w(Wmat[4]);
        if (tid < 64) bias_lds[tid] = bvec[4][tid];
        __syncthreads();
        {
            f32x4_t a0 = {0.f,0.f,0.f,0.f}, a1 = {0.f,0.f,0.f,0.f};
            #pragma unroll
            for (int kh = 0; kh < 2; ++kh) {
                const int ck = kh * 4 + q4;
                const int ar = srow + lr;
                const s16x8_t af = *reinterpret_cast<const s16x8_t*>(&a_lds[ar * 64 + ((ck ^ (ar & 7)) * 8)]);
                const int c0 = pcol + lr;
                const int c1 = pcol + 16 + lr;
                const s16x8_t b0  = *reinterpret_cast<const s16x8_t*>(&w_lds[c0 * 64 + ((ck ^ (c0 & 7)) * 8)]);
                const s16x8_t b1v = *reinterpret_cast<const s16x8_t*>(&w_lds[c1 * 64 + ((ck ^ (c1 & 7)) * 8)]);
                a0 = __builtin_amdgcn_mfma_f32_16x16x32_bf16(af, b0,  a0, 0, 0, 0);
                a1 = __builtin_amdgcn_mfma_f32_16x16x32_bf16(af, b1v, a1, 0, 0, 0);
            }
            #pragma unroll
            for (int rg = 0; rg < 4; ++rg) {
                const int tr = srow + q4 * 4 + rg;
                const int c0 = pcol + lr;
                const int c1 = pcol + 16 + lr;
                ky_lds[tr * 68 + c0] = a0[rg] + bias_lds[c0] + ky_lds[tr * 68 + c0];
                ky_lds[tr * 68 + c1] = a1[rg] + bias_lds[c1] + ky_lds[tr * 68 + c1];
            }
        }
        __syncthreads();

        // ---- LayerNorm + residual accumulate ----
        #pragma unroll
        for (int tt = 0; tt < 8; ++tt) {
            const int t = wv * 8 + tt;
            const float a = ky_lds[t * 68 + l];
            float s = a;
            #pragma unroll
            for (int m = 1; m < 64; m <<= 1) s += __shfl_xor(s, m, 64);
            const float mu = s * 0.015625f;
            const float d  = a - mu;
            float vsum = d * d;
            #pragma unroll
            for (int m = 1; m < 64; m <<= 1) vsum += __shfl_xor(vsum, m, 64);
            const float rs   = frsq(vsum * 0.015625f + 1e-5f);
            const float an   = d * rs * lng_lds[l] + lnb_lds[l];
            const float rnew = res_reg[tt] + an;
            res_reg[tt] = rnew;
            cur_reg[tt] = rnew;
            a_lds[t * 64 + ((((l >> 3) ^ (t & 7)) * 8) + (l & 7))] = f2bf(rnew);
        }
        // next stage's first phase begins with __syncthreads()
    }

    // ---------------- output head: leaky(res @ Wout + bout, 0.1), 5 copies ----------------
    const float wo = Wout[l];
    const float bo = bout[0];
    #pragma unroll
    for (int tt = 0; tt < 8; ++tt) {
        const int t = wv * 8 + tt;
        float p = res_reg[tt] * wo;
        #pragma unroll
        for (int m = 1; m < 64; m <<= 1) p += __shfl_xor(p, m, 64);
        float o = p + bo;
        o = o >= 0.f ? o : 0.1f * o;
        if (l < 5) out[(size_t)l * NTOK + n0 + t] = o;
    }
}

extern "C" void kernel_launch(void* const* d_in, const int* in_sizes, int n_in,
                              void* d_out, int out_size, void* d_ws, size_t ws_size,
                              hipStream_t stream) {
    const float* x    = (const float*)d_in[0];
    const float* W1   = (const float*)d_in[1];
    const float* b1   = (const float*)d_in[2];
    const float* Wq   = (const float*)d_in[3];
    const float* bq   = (const float*)d_in[4];
    const float* Wk   = (const float*)d_in[5];
    const float* bk   = (const float*)d_in[6];
    const float* Wv   = (const float*)d_in[7];
    const float* bv   = (const float*)d_in[8];
    const float* Wf1  = (const float*)d_in[9];
    const float* bf1  = (const float*)d_in[10];
    const float* Wf2  = (const float*)d_in[11];
    const float* bf2  = (const float*)d_in[12];
    const float* lngp = (const float*)d_in[13];
    const float* lnbp = (const float*)d_in[14];
    const float* Wout = (const float*)d_in[15];
    const float* bout = (const float*)d_in[16];
    float* outp = (float*)d_out;

    dim3 grid(NTOK / TB);
    dim3 block(256);
    hipLaunchKernelGGL(tf3_kernel, grid, block, 0, stream,
                       x, W1, b1, Wq, bq, Wk, bk, Wv, bv,
                       Wf1, bf1, Wf2, bf2, lngp, lnbp, Wout, bout, outp);
}

// Round 2
// 58.285 us; speedup vs baseline: 1.0770x; 1.0770x over previous
//
#include <hip/hip_runtime.h>

#define NTOK 16384
#define TB 16

typedef float f32x4_t __attribute__((ext_vector_type(4)));
typedef short s16x8_t __attribute__((ext_vector_type(8)));
typedef short s16x4_t __attribute__((ext_vector_type(4)));

__device__ __forceinline__ unsigned short f2bf(float f) {
    unsigned int x = __float_as_uint(f);
    x += 0x7fffu + ((x >> 16) & 1u);
    return (unsigned short)(x >> 16);
}
__device__ __forceinline__ float fexp2(float x) {
#if __has_builtin(__builtin_amdgcn_exp2f)
    return __builtin_amdgcn_exp2f(x);
#else
    return exp2f(x);
#endif
}
__device__ __forceinline__ float frcp(float x) {
#if __has_builtin(__builtin_amdgcn_rcpf)
    return __builtin_amdgcn_rcpf(x);
#else
    return 1.0f / x;
#endif
}
__device__ __forceinline__ float frsq(float x) {
#if __has_builtin(__builtin_amdgcn_rsqf)
    return __builtin_amdgcn_rsqf(x);
#else
    return rsqrtf(x);
#endif
}

__global__ __launch_bounds__(256, 4)
void tf3_kernel(const float* __restrict__ x,
                const float* __restrict__ W1, const float* __restrict__ b1,
                const float* __restrict__ Wq, const float* __restrict__ bq,
                const float* __restrict__ Wk, const float* __restrict__ bk,
                const float* __restrict__ Wv, const float* __restrict__ bv,
                const float* __restrict__ Wf1, const float* __restrict__ bf1,
                const float* __restrict__ Wf2, const float* __restrict__ bf2,
                const float* __restrict__ lng, const float* __restrict__ lnb,
                const float* __restrict__ Wout, const float* __restrict__ bout,
                float* __restrict__ out)
{
    // LDS ~38.25 KB -> 4 blocks/CU. Biases/LN params come from L1 scalar loads.
    __shared__ __align__(16) unsigned short w3_lds[3 * 64 * 64];  // 24576 B, bf16 [m][k] swizzled
    __shared__ __align__(16) unsigned short a_lds[TB * 64];       //  2048 B, bf16 activations swizzled
    __shared__ __align__(16) float q_lds[TB * 64];                //  4096 B
    __shared__ __align__(16) float ky_lds[TB * 68];               //  4352 B (pad 68 for F1 A-reads)
    __shared__ __align__(16) float v_lds[TB * 64];                //  4096 B

    const int tid = threadIdx.x;
    const int wv  = tid >> 6;       // wave 0..3
    const int l   = tid & 63;       // lane
    const int n0  = blockIdx.x * TB;

    const int lr  = l & 15;         // row (A) / col (B/C) within 16
    const int q4  = l >> 4;         // k-quad / C row group
    const int pcol = wv * 16;       // wave's output-column tile
    const int c    = pcol + lr;     // this lane's output column in epilogues

    // cooperative-reduction geometry: group g (16 lanes) owns token wv*4+g
    const int g  = q4;
    const int e  = lr;
    const int tg = wv * 4 + g;

    float res_reg[4], cur_reg[4];

    // global f32 W[k][m] -> w3_lds[slot] bf16 [m][k], XOR-swizzled 8-chunks
    auto loadW = [&](const float* __restrict__ Wg, int slot, int cc) {
        s16x8_t pk;
        #pragma unroll
        for (int i = 0; i < 8; ++i)
            pk[i] = (short)f2bf(Wg[(cc * 8 + i) * 64 + l]);      // coalesced across lanes
        *reinterpret_cast<s16x8_t*>(&w3_lds[slot * 4096 + l * 64 + ((cc ^ (l & 7)) * 8)]) = pk;
    };
    // one 16x16 output tile, K=64, A from a_lds, B from w3 slot base
    auto mm16 = [&](const unsigned short* __restrict__ bbase) -> f32x4_t {
        f32x4_t acc = {0.f, 0.f, 0.f, 0.f};
        #pragma unroll
        for (int kh = 0; kh < 2; ++kh) {
            const int ck = kh * 4 + q4;
            const s16x8_t af = *reinterpret_cast<const s16x8_t*>(&a_lds[lr * 64 + ((ck ^ (lr & 7)) * 8)]);
            const s16x8_t bf = *reinterpret_cast<const s16x8_t*>(&bbase[c * 64 + ((ck ^ (c & 7)) * 8)]);
            acc = __builtin_amdgcn_mfma_f32_16x16x32_bf16(af, bf, acc, 0, 0, 0);
        }
        return acc;
    };

    // ---------------- stage 0: h = x @ W1 + b1 (K=256, 4 chunks) ----------------
    f32x4_t acch = {0.f, 0.f, 0.f, 0.f};
    for (int kc = 0; kc < 4; ++kc) {
        __syncthreads();
        {   // stage x chunk: 16 rows x 64 cols, 1 float4 per thread
            const int r  = tid >> 4;
            const int c4 = (tid & 15) * 4;
            const float4 u = *reinterpret_cast<const float4*>(x + (size_t)(n0 + r) * 256 + kc * 64 + c4);
            s16x4_t pk;
            pk[0] = (short)f2bf(u.x); pk[1] = (short)f2bf(u.y);
            pk[2] = (short)f2bf(u.z); pk[3] = (short)f2bf(u.w);
            const int cc = c4 >> 3, e0 = c4 & 7;
            *reinterpret_cast<s16x4_t*>(&a_lds[r * 64 + ((cc ^ (r & 7)) * 8) + e0]) = pk;
        }
        loadW(W1 + kc * 4096, 0, wv * 2 + 0);
        loadW(W1 + kc * 4096, 0, wv * 2 + 1);
        __syncthreads();
        #pragma unroll
        for (int kh = 0; kh < 2; ++kh) {
            const int ck = kh * 4 + q4;
            const s16x8_t af = *reinterpret_cast<const s16x8_t*>(&a_lds[lr * 64 + ((ck ^ (lr & 7)) * 8)]);
            const s16x8_t bf = *reinterpret_cast<const s16x8_t*>(&w3_lds[c * 64 + ((ck ^ (c & 7)) * 8)]);
            acch = __builtin_amdgcn_mfma_f32_16x16x32_bf16(af, bf, acch, 0, 0, 0);
        }
    }
    {   // epilogue: h -> q_lds (row-major redistribute)
        const float b1v = b1[c];
        #pragma unroll
        for (int rg = 0; rg < 4; ++rg)
            q_lds[(q4 * 4 + rg) * 64 + c] = acch[rg] + b1v;
    }
    __syncthreads();
    #pragma unroll
    for (int tt = 0; tt < 4; ++tt) {     // cur = h, res = leaky(h, 0.1)
        const int t = wv * 4 + tt;
        const float h = q_lds[t * 64 + l];
        cur_reg[tt] = h;
        res_reg[tt] = h >= 0.f ? h : 0.1f * h;
        a_lds[t * 64 + (((l >> 3) ^ (t & 7)) * 8) + (l & 7)] = f2bf(h);
    }

    // ---------------- 3 attention stages (5 barriers each) ----------------
    for (int st = 0; st < 3; ++st) {
        const float* Wq_s  = Wq  + st * 4096;
        const float* Wk_s  = Wk  + st * 4096;
        const float* Wv_s  = Wv  + st * 4096;
        const float* Wf1_s = Wf1 + st * 4096;
        const float* Wf2_s = Wf2 + st * 4096;

        // phaseW (same interval as previous LN): load Wq,Wk,Wv -> w3 slots 0..2
        #pragma unroll
        for (int i = 0; i < 6; ++i) {
            const int u = wv * 6 + i;          // 0..23 = 3 mats x 8 chunks
            const int m = u >> 3;
            loadW(m == 0 ? Wq_s : (m == 1 ? Wk_s : Wv_s), m, u & 7);
        }
        __syncthreads();                        // B1

        // QKV: 3 GEMMs back-to-back
        {
            f32x4_t aq = mm16(&w3_lds[0]);
            f32x4_t ak = mm16(&w3_lds[4096]);
            f32x4_t av = mm16(&w3_lds[8192]);
            const float bqv = bq[st * 64 + c];
            const float bkv = bk[st * 64 + c];
            const float bvv = bv[st * 64 + c];
            #pragma unroll
            for (int rg = 0; rg < 4; ++rg) {
                const int tr = q4 * 4 + rg;
                q_lds[tr * 64 + c]  = aq[rg] + bqv;
                ky_lds[tr * 68 + c] = ak[rg] + bkv;
                v_lds[tr * 64 + c]  = av[rg] + bvv;
            }
        }
        __syncthreads();                        // B2

        // attn phase: load F-weights (overlaps), cooperative k-range, per-token softmax
        #pragma unroll
        for (int i = 0; i < 4; ++i) {
            const int u = wv * 4 + i;          // 0..15 = 2 mats x 8 chunks
            loadW((u >> 3) == 0 ? Wf1_s : Wf2_s, u >> 3, u & 7);
        }
        float kmx, kmn;
        {   // group g reduces token tg's K row (16 lanes x 4 elems)
            const float4 kv = *reinterpret_cast<const float4*>(&ky_lds[tg * 68 + e * 4]);
            kmx = fmaxf(fmaxf(kv.x, kv.y), fmaxf(kv.z, kv.w));
            kmn = fminf(fminf(kv.x, kv.y), fminf(kv.z, kv.w));
            #pragma unroll
            for (int m = 1; m < 16; m <<= 1) {
                kmx = fmaxf(kmx, __shfl_xor(kmx, m, 64));
                kmn = fminf(kmn, __shfl_xor(kmn, m, 64));
            }
        }
        float kmax_t[4], kmin_t[4];
        #pragma unroll
        for (int tt = 0; tt < 4; ++tt) {
            kmax_t[tt] = __shfl(kmx, tt * 16, 64);
            kmin_t[tt] = __shfl(kmn, tt * 16, 64);
        }
        #pragma unroll
        for (int tt = 0; tt < 4; ++tt) {
            const int t = wv * 4 + tt;
            const float qs = q_lds[t * 64 + l] * 1.44269504088896340736f;   // q*log2(e)
            const float m2 = fmaxf(qs * kmax_t[tt], qs * kmin_t[tt]);       // exact row max (rank-1)
            float s0 = 0.f, s1 = 0.f, p0 = 0.f, p1 = 0.f;
            #pragma unroll
            for (int j = 0; j < 64; j += 4) {
                const float4 kj = *reinterpret_cast<const float4*>(&ky_lds[t * 68 + j]); // uniform bcast
                const float4 vj = *reinterpret_cast<const float4*>(&v_lds[t * 64 + j]);
                const float e0 = fexp2(fmaf(qs, kj.x, -m2));
                const float e1 = fexp2(fmaf(qs, kj.y, -m2));
                const float e2 = fexp2(fmaf(qs, kj.z, -m2));
                const float e3 = fexp2(fmaf(qs, kj.w, -m2));
                s0 += e0 + e2; s1 += e1 + e3;
                p0 = fmaf(e0, vj.x, p0); p1 = fmaf(e1, vj.y, p1);
                p0 = fmaf(e2, vj.z, p0); p1 = fmaf(e3, vj.w, p1);
            }
            const float y = (p0 + p1) * frcp(s0 + s1) + cur_reg[tt];
            ky_lds[t * 68 + l] = y;   // overwrite K row (fully consumed; wave-private rows)
        }
        __syncthreads();                        // B3

        // F1: h1 = leaky(Y @ Wf1 + bf1, 0.01) -> a_lds bf16
        {
            f32x4_t acc = {0.f, 0.f, 0.f, 0.f};
            #pragma unroll
            for (int kh = 0; kh < 2; ++kh) {
                const float* yp = &ky_lds[lr * 68 + kh * 32 + q4 * 8];
                const float4 y0 = *reinterpret_cast<const float4*>(yp);
                const float4 y1 = *reinterpret_cast<const float4*>(yp + 4);
                s16x8_t af;
                af[0] = (short)f2bf(y0.x); af[1] = (short)f2bf(y0.y);
                af[2] = (short)f2bf(y0.z); af[3] = (short)f2bf(y0.w);
                af[4] = (short)f2bf(y1.x); af[5] = (short)f2bf(y1.y);
                af[6] = (short)f2bf(y1.z); af[7] = (short)f2bf(y1.w);
                const int ck = kh * 4 + q4;
                const s16x8_t bf = *reinterpret_cast<const s16x8_t*>(&w3_lds[c * 64 + ((ck ^ (c & 7)) * 8)]);
                acc = __builtin_amdgcn_mfma_f32_16x16x32_bf16(af, bf, acc, 0, 0, 0);
            }
            const float bfv = bf1[st * 64 + c];
            #pragma unroll
            for (int rg = 0; rg < 4; ++rg) {
                const int tr = q4 * 4 + rg;
                float h = acc[rg] + bfv;
                h = h >= 0.f ? h : 0.01f * h;
                a_lds[tr * 64 + (((c >> 3) ^ (tr & 7)) * 8) + (c & 7)] = f2bf(h);
            }
        }
        __syncthreads();                        // B4

        // F2: A = h1 @ Wf2 + bf2 + Y -> ky_lds
        {
            f32x4_t acc = mm16(&w3_lds[4096]);
            const float bfv = bf2[st * 64 + c];
            #pragma unroll
            for (int rg = 0; rg < 4; ++rg) {
                const int tr = q4 * 4 + rg;
                ky_lds[tr * 68 + c] += acc[rg] + bfv;
            }
        }
        __syncthreads();                        // B5

        // LN (cooperative, two-pass) + residual; write bf16(cur) for next stage
        float s_sum, vsum;
        float4 av4;
        {
            av4 = *reinterpret_cast<const float4*>(&ky_lds[tg * 68 + e * 4]);
            s_sum = av4.x + av4.y + av4.z + av4.w;
            #pragma unroll
            for (int m = 1; m < 16; m <<= 1) s_sum += __shfl_xor(s_sum, m, 64);
            const float mug = s_sum * 0.015625f;
            const float d0 = av4.x - mug, d1 = av4.y - mug, d2 = av4.z - mug, d3 = av4.w - mug;
            vsum = d0 * d0 + d1 * d1 + d2 * d2 + d3 * d3;
            #pragma unroll
            for (int m = 1; m < 16; m <<= 1) vsum += __shfl_xor(vsum, m, 64);
            s_sum = mug;                       // s_sum now holds this group's mu
        }
        const float lngv = lng[st * 64 + l];
        const float lnbv = lnb[st * 64 + l];
        #pragma unroll
        for (int tt = 0; tt < 4; ++tt) {
            const int t = wv * 4 + tt;
            const float mu = __shfl(s_sum, tt * 16, 64);
            const float vv = __shfl(vsum, tt * 16, 64);
            const float rs = frsq(vv * 0.015625f + 1e-5f);
            const float a  = ky_lds[t * 68 + l];
            const float an = (a - mu) * rs * lngv + lnbv;
            const float rnew = res_reg[tt] + an;
            res_reg[tt] = rnew;
            cur_reg[tt] = rnew;
            a_lds[t * 64 + (((l >> 3) ^ (t & 7)) * 8) + (l & 7)] = f2bf(rnew);
        }
        // next iteration's phaseW runs in this same barrier interval; B1 protects reads
    }

    // ---------------- head: leaky(res @ Wout + bout, 0.1), 5 output copies ----------------
    const float wo = Wout[l];
    const float bo = bout[0];
    #pragma unroll
    for (int tt = 0; tt < 4; ++tt)
        q_lds[(wv * 4 + tt) * 64 + l] = res_reg[tt] * wo;   // wave-private rows
    {
        const float4 pv = *reinterpret_cast<const float4*>(&q_lds[tg * 64 + e * 4]);
        float p = pv.x + pv.y + pv.z + pv.w;
        #pragma unroll
        for (int m = 1; m < 16; m <<= 1) p += __shfl_xor(p, m, 64);
        if (e == 0) {
            float o = p + bo;
            o = o >= 0.f ? o : 0.1f * o;
            #pragma unroll
            for (int c5 = 0; c5 < 5; ++c5)
                out[(size_t)c5 * NTOK + n0 + tg] = o;
        }
    }
}

extern "C" void kernel_launch(void* const* d_in, const int* in_sizes, int n_in,
                              void* d_out, int out_size, void* d_ws, size_t ws_size,
                              hipStream_t stream) {
    const float* x    = (const float*)d_in[0];
    const float* W1   = (const float*)d_in[1];
    const float* b1   = (const float*)d_in[2];
    const float* Wq   = (const float*)d_in[3];
    const float* bq   = (const float*)d_in[4];
    const float* Wk   = (const float*)d_in[5];
    const float* bk   = (const float*)d_in[6];
    const float* Wv   = (const float*)d_in[7];
    const float* bv   = (const float*)d_in[8];
    const float* Wf1  = (const float*)d_in[9];
    const float* bf1  = (const float*)d_in[10];
    const float* Wf2  = (const float*)d_in[11];
    const float* bf2  = (const float*)d_in[12];
    const float* lngp = (const float*)d_in[13];
    const float* lnbp = (const float*)d_in[14];
    const float* Wout = (const float*)d_in[15];
    const float* bout = (const float*)d_in[16];
    float* outp = (float*)d_out;

    dim3 grid(NTOK / TB);
    dim3 block(256);
    hipLaunchKernelGGL(tf3_kernel, grid, block, 0, stream,
                       x, W1, b1, Wq, bq, Wk, bk, Wv, bv,
                       Wf1, bf1, Wf2, bf2, lngp, lnbp, Wout, bout, outp);
}